// Round 6
// baseline (513.724 us; speedup 1.0000x reference)
//
#include <hip/hip_runtime.h>

#define HH 192
#define WW 256
#define NPIX (HH*WW)   // 49152
#define NSEG (NPIX/64) // 768

__device__ __forceinline__ float lrelu(float v) { return v > 0.0f ? v : 0.01f * v; }

#define GAS1(p) (const __attribute__((address_space(1))) void*)(p)
#define LAS3(p) (__attribute__((address_space(3))) void*)(p)

// ============================================================================
// k_tw: pre-transpose Wcl1/Wr1 (128x128) and Wm1 (32x128) into workspace so
// k_fused1 can stage weight tiles with global_load_lds (linear LDS dest).
// R12: destinations alias the bh/ebb region (147KB < 196KB) — NO workspace
// growth (R11 wrote past ws_size -> device fault -> container failure).
// Lifetime: k_tw -> k_fused1 reads -> k_hist/k_scanA overwrite later. Safe.
// ============================================================================
__global__ void k_tw(const float* __restrict__ Wc, const float* __restrict__ Wr,
                     const float* __restrict__ Wm,
                     float* __restrict__ Wct, float* __restrict__ Wrt,
                     float* __restrict__ Wmt)
{
    const int b = blockIdx.x, tid = threadIdx.x;
    const float* __restrict__ src = (b == 0) ? Wc : (b == 1) ? Wr : Wm;
    float* __restrict__ dst       = (b == 0) ? Wct : (b == 1) ? Wrt : Wmt;
    const int olog = (b == 2) ? 5 : 7;
    const int n    = 128 << olog;
    for (int idx = tid; idx < n; idx += 256) {
        int k = idx >> olog, o = idx & ((1 << olog) - 1);
        dst[idx] = src[o * 128 + k];   // dst[k][o] = src[o][k]; coalesced writes
    }
}

// ============================================================================
// k_fused1 (R11 structure): y=0 -> x_t (Wcl1), y=1 -> r_t (Wr1), y=2 -> mask.
// Staging via global_load_lds into DOUBLE-BUFFERED unpadded LDS tiles
// (statically-named As0/Ws0 and As1/Ws1, loop unrolled x2 — NOT R7's
// runtime-swapped pointers, which spilled acc). STAGE(next) issues before
// COMPUTE(cur); barrier's vmcnt(0) drain lands after the FMA block.
// Ledger: R7 reg-dbuf = spill (670us). R9 mask-fusion = -6us.
// R10 bounds-4 = -5us (reg-starved staging). Keep bounds 3.
// ============================================================================
__global__ __launch_bounds__(256, 3) void k_fused1(
    const float* __restrict__ X,
    const float* __restrict__ Wct,  const float* __restrict__ bcl1,
    const float* __restrict__ Wrt,  const float* __restrict__ br1,
    const float* __restrict__ Wmt,  const float* __restrict__ bm1,
    const float* __restrict__ Wm2,  const float* __restrict__ bm2,
    const float* __restrict__ Wm3,  const float* __restrict__ bm3,
    float* __restrict__ x_t, float* __restrict__ r_t,
    float* __restrict__ out)
{
    __shared__ float smem[8192];                      // 32 KiB
    float (*As0)[128] = (float(*)[128])(smem);        // [16][128]
    float (*Ws0)[128] = (float(*)[128])(smem + 2048);
    float (*As1)[128] = (float(*)[128])(smem + 4096);
    float (*Ws1)[128] = (float(*)[128])(smem + 6144);
    float (*m1buf)[33] = (float(*)[33])smem;          // y=2 epilogue alias

    const int tid = threadIdx.x;
    const int l   = tid & 63;        // lane
    const int wv  = tid >> 6;        // wave id (0..3)
    const int q0  = blockIdx.x * 128;

// stage one 16x128 X-tile chunk pair + matching W-tile chunk pair (wave wv
// handles 1KB chunks 2wv, 2wv+1 of each; chunk c = rows 2c,2c+1)
#define STAGE_MAIN(Ab, Wb, Wsrc, kb) do {                                     \
    int c_ = 2 * wv;                                                          \
    int row0_ = 2 * c_ + (l >> 5);                                            \
    int col_  = (l & 31) * 4;                                                 \
    __builtin_amdgcn_global_load_lds(                                         \
        GAS1(X + (size_t)((kb) + row0_) * NPIX + q0 + col_),                  \
        LAS3(&Ab[0][0] + c_ * 256), 16, 0, 0);                                \
    __builtin_amdgcn_global_load_lds(                                         \
        GAS1(Wsrc + ((kb) + row0_) * 128 + col_),                             \
        LAS3(&Wb[0][0] + c_ * 256), 16, 0, 0);                                \
    int row1_ = row0_ + 2;                                                    \
    __builtin_amdgcn_global_load_lds(                                         \
        GAS1(X + (size_t)((kb) + row1_) * NPIX + q0 + col_),                  \
        LAS3(&Ab[0][0] + c_ * 256 + 256), 16, 0, 0);                          \
    __builtin_amdgcn_global_load_lds(                                         \
        GAS1(Wsrc + ((kb) + row1_) * 128 + col_),                             \
        LAS3(&Wb[0][0] + c_ * 256 + 256), 16, 0, 0);                          \
} while (0)

#define COMPUTE_MAIN(Ab, Wb) do {                                             \
    _Pragma("unroll")                                                         \
    for (int kk = 0; kk < 16; ++kk) {                                         \
        float4 a0 = *(const float4*)(&Ab[kk][tc * 4]);                        \
        float4 a1 = *(const float4*)(&Ab[kk][64 + tc * 4]);                   \
        float4 w0 = *(const float4*)(&Wb[kk][tr * 4]);                        \
        float4 w1 = *(const float4*)(&Wb[kk][64 + tr * 4]);                   \
        float av[8] = {a0.x,a0.y,a0.z,a0.w,a1.x,a1.y,a1.z,a1.w};              \
        float wvv[8] = {w0.x,w0.y,w0.z,w0.w,w1.x,w1.y,w1.z,w1.w};             \
        _Pragma("unroll")                                                     \
        for (int i = 0; i < 8; ++i)                                           \
            _Pragma("unroll")                                                 \
            for (int j = 0; j < 8; ++j)                                       \
                acc[i][j] = fmaf(av[i], wvv[j], acc[i][j]);                   \
    }                                                                         \
} while (0)

    if (blockIdx.y == 2) {
        // ---- mask branch: same 2-phase global_load_lds structure, 32-out W --
        float (*Wm0)[32] = (float(*)[32])(smem + 2048);   // inside Ws0 slot
        float (*Wm1b)[32] = (float(*)[32])(smem + 6144);  // inside Ws1 slot
        const int mc = tid & 31;
        const int mr = tid >> 5;
        float accM[4][4];
        #pragma unroll
        for (int i = 0; i < 4; ++i)
            #pragma unroll
            for (int j = 0; j < 4; ++j)
                accM[i][j] = bm1[mr * 4 + j];

#define STAGE_MASK(Ab, Wmb, kb) do {                                          \
    int c_ = 2 * wv;                                                          \
    int row0_ = 2 * c_ + (l >> 5);                                            \
    int col_  = (l & 31) * 4;                                                 \
    __builtin_amdgcn_global_load_lds(                                         \
        GAS1(X + (size_t)((kb) + row0_) * NPIX + q0 + col_),                  \
        LAS3(&Ab[0][0] + c_ * 256), 16, 0, 0);                                \
    int row1_ = row0_ + 2;                                                    \
    __builtin_amdgcn_global_load_lds(                                         \
        GAS1(X + (size_t)((kb) + row1_) * NPIX + q0 + col_),                  \
        LAS3(&Ab[0][0] + c_ * 256 + 256), 16, 0, 0);                          \
    if (wv < 2) {                                                             \
        int mrow_ = wv * 8 + (l >> 3);                                        \
        int mcol_ = (l & 7) * 4;                                              \
        __builtin_amdgcn_global_load_lds(                                     \
            GAS1(Wmt + ((kb) + mrow_) * 32 + mcol_),                          \
            LAS3(&Wmb[0][0] + wv * 256), 16, 0, 0);                           \
    }                                                                         \
} while (0)

#define COMPUTE_MASK(Ab, Wmb) do {                                            \
    _Pragma("unroll")                                                         \
    for (int kk = 0; kk < 16; ++kk) {                                         \
        float4 a = *(const float4*)(&Ab[kk][mc * 4]);                         \
        float4 w = *(const float4*)(&Wmb[kk][mr * 4]);                        \
        float av[4] = {a.x,a.y,a.z,a.w};                                      \
        float wvv[4] = {w.x,w.y,w.z,w.w};                                     \
        _Pragma("unroll")                                                     \
        for (int i = 0; i < 4; ++i)                                           \
            _Pragma("unroll")                                                 \
            for (int j = 0; j < 4; ++j)                                       \
                accM[i][j] = fmaf(av[i], wvv[j], accM[i][j]);                 \
    }                                                                         \
} while (0)

        STAGE_MASK(As0, Wm0, 0);
        __syncthreads();
        for (int k0 = 0; k0 < 128; k0 += 32) {
            if (k0 + 16 < 128) STAGE_MASK(As1, Wm1b, k0 + 16);
            COMPUTE_MASK(As0, Wm0);
            __syncthreads();
            if (k0 + 32 < 128) STAGE_MASK(As0, Wm0, k0 + 32);
            COMPUTE_MASK(As1, Wm1b);
            __syncthreads();
        }
        #pragma unroll
        for (int i = 0; i < 4; ++i)
            #pragma unroll
            for (int j = 0; j < 4; ++j)
                m1buf[mc * 4 + i][mr * 4 + j] = lrelu(accM[i][j]);
        __syncthreads();
        if (tid < 128) {
            float m3 = bm3[0];
            #pragma unroll 2
            for (int j = 0; j < 16; ++j) {
                float s = bm2[j];
                #pragma unroll
                for (int k = 0; k < 32; ++k)
                    s = fmaf(Wm2[j * 32 + k], m1buf[tid][k], s);
                m3 = fmaf(Wm3[j], lrelu(s), m3);
            }
            out[NPIX + q0 + tid] = lrelu(m3);
        }
        return;
    }

    const float* __restrict__ Wt   = (blockIdx.y == 0) ? Wct : Wrt;
    const float* __restrict__ bias = (blockIdx.y == 0) ? bcl1 : br1;
    float* __restrict__ outp       = (blockIdx.y == 0) ? x_t : r_t;

    const int tc = tid & 15;
    const int tr = tid >> 4;

    float acc[8][8];
    #pragma unroll
    for (int i = 0; i < 8; ++i)
        #pragma unroll
        for (int j = 0; j < 8; ++j)
            acc[i][j] = bias[(j >> 2) * 64 + tr * 4 + (j & 3)];

    STAGE_MAIN(As0, Ws0, Wt, 0);
    __syncthreads();
    for (int k0 = 0; k0 < 128; k0 += 32) {
        if (k0 + 16 < 128) STAGE_MAIN(As1, Ws1, Wt, k0 + 16);
        COMPUTE_MAIN(As0, Ws0);
        __syncthreads();
        if (k0 + 32 < 128) STAGE_MAIN(As0, Ws0, Wt, k0 + 32);
        COMPUTE_MAIN(As1, Ws1);
        __syncthreads();
    }

    #pragma unroll
    for (int i = 0; i < 8; ++i) {
        int px = (i >> 2) * 64 + tc * 4 + (i & 3);
        int q  = q0 + px;
        int np = (q & 255) * 192 + (q >> 8);
        float* op = outp + (size_t)np * 128;
        #pragma unroll
        for (int jg = 0; jg < 2; ++jg) {
            float4 o;
            o.x = lrelu(acc[i][jg*4+0]); o.y = lrelu(acc[i][jg*4+1]);
            o.z = lrelu(acc[i][jg*4+2]); o.w = lrelu(acc[i][jg*4+3]);
            *(float4*)(op + jg * 64 + tr * 4) = o;
        }
    }
}

// ============================================================================
// k1b: x2 = lrelu(Wcl21@x), cl1 = Wcl31@x2 + argmax -> inds1_q (q-order).
// (exact R6 text)
// ============================================================================
__global__ __launch_bounds__(256, 2) void k1b(
    const float* __restrict__ x_t,
    const float* __restrict__ Wcl21, const float* __restrict__ bcl21,
    const float* __restrict__ Wcl31, const float* __restrict__ bcl31,
    int* __restrict__ inds1_q)
{
    __shared__ float smem[12672];
    float (*As)[132]     = (float(*)[132])smem;
    float (*Ws)[132]     = (float(*)[132])(smem + 2112);
    float (*W31)[132]    = (float(*)[132])smem;
    float (*x2t)[132]    = (float(*)[132])(smem + 4224);
    float (*cl1buf)[33]  = (float(*)[33]) (smem + 4224);

    const int tid = threadIdx.x;
    const int n0  = blockIdx.x * 128;
    const int tcA = tid & 15, trA = tid >> 4;
    const int tcB = tid & 31, trB = tid >> 5;

    float accB[4][4];
    #pragma unroll
    for (int i = 0; i < 4; ++i)
        #pragma unroll
        for (int j = 0; j < 4; ++j)
            accB[i][j] = bcl31[trB * 4 + j];

    for (int h = 0; h < 2; ++h) {
        float acc2[2][4][4];
        #pragma unroll
        for (int gi = 0; gi < 2; ++gi)
            #pragma unroll
            for (int i = 0; i < 4; ++i)
                #pragma unroll
                for (int j = 0; j < 4; ++j)
                    acc2[gi][i][j] = bcl21[h * 64 + trA * 4 + j];

        for (int k0 = 0; k0 < 128; k0 += 16) {
            #pragma unroll
            for (int p = 0; p < 2; ++p) {
                int lin = p * 1024 + tid * 4;
                int px = lin >> 4, kc = lin & 15;
                float4 v = *(const float4*)(x_t + (size_t)(n0 + px) * 128 + k0 + kc);
                As[kc + 0][px] = v.x; As[kc + 1][px] = v.y;
                As[kc + 2][px] = v.z; As[kc + 3][px] = v.w;
            }
            {
                int r = tid >> 2, kc = (tid & 3) * 4;
                float4 v = *(const float4*)(Wcl21 + (h * 64 + r) * 128 + k0 + kc);
                Ws[kc + 0][r] = v.x; Ws[kc + 1][r] = v.y;
                Ws[kc + 2][r] = v.z; Ws[kc + 3][r] = v.w;
            }
            __syncthreads();
            #pragma unroll
            for (int kk = 0; kk < 16; ++kk) {
                float4 a0 = *(const float4*)(&As[kk][tcA * 4]);
                float4 a1 = *(const float4*)(&As[kk][64 + tcA * 4]);
                float4 w  = *(const float4*)(&Ws[kk][trA * 4]);
                float av0[4] = {a0.x,a0.y,a0.z,a0.w};
                float av1[4] = {a1.x,a1.y,a1.z,a1.w};
                float wv[4]  = {w.x,w.y,w.z,w.w};
                #pragma unroll
                for (int i = 0; i < 4; ++i)
                    #pragma unroll
                    for (int j = 0; j < 4; ++j) {
                        acc2[0][i][j] = fmaf(av0[i], wv[j], acc2[0][i][j]);
                        acc2[1][i][j] = fmaf(av1[i], wv[j], acc2[1][i][j]);
                    }
            }
            __syncthreads();
        }
        #pragma unroll
        for (int j = 0; j < 4; ++j) {
            int row = trA * 4 + j;
            #pragma unroll
            for (int gi = 0; gi < 2; ++gi) {
                float4 o;
                o.x = lrelu(acc2[gi][0][j]); o.y = lrelu(acc2[gi][1][j]);
                o.z = lrelu(acc2[gi][2][j]); o.w = lrelu(acc2[gi][3][j]);
                *(float4*)(&x2t[row][gi * 64 + tcA * 4]) = o;
            }
        }
        __syncthreads();
        #pragma unroll
        for (int p = 0; p < 4; ++p) {
            int lin = p * 1024 + tid * 4;
            int row = lin >> 7, kc = lin & 127;
            *(float4*)(&W31[row][kc]) = *(const float4*)(Wcl31 + row * 128 + kc);
        }
        __syncthreads();
        for (int k = 0; k < 64; ++k) {
            float4 a = *(const float4*)(&x2t[k][tcB * 4]);
            float av[4] = {a.x,a.y,a.z,a.w};
            float wv[4];
            #pragma unroll
            for (int j = 0; j < 4; ++j) wv[j] = W31[trB * 4 + j][h * 64 + k];
            #pragma unroll
            for (int i = 0; i < 4; ++i)
                #pragma unroll
                for (int j = 0; j < 4; ++j)
                    accB[i][j] = fmaf(av[i], wv[j], accB[i][j]);
        }
        __syncthreads();
    }

    #pragma unroll
    for (int i = 0; i < 4; ++i)
        #pragma unroll
        for (int j = 0; j < 4; ++j)
            cl1buf[tcB * 4 + i][trB * 4 + j] = accB[i][j];
    __syncthreads();
    if (tid < 128) {
        float bv = cl1buf[tid][0]; int bi = 0;
        #pragma unroll
        for (int c = 1; c < 32; ++c) {
            float v = cl1buf[tid][c];
            if (v > bv) { bv = v; bi = c; }
        }
        int n = n0 + tid;
        int w = n / 192, hh = n - w * 192;
        inds1_q[hh * 256 + w] = bi;
    }
}

// ============================================================================
// k_hist: 192 blocks; per-64-seg ballot histogram -> bh[seg][32] (unchanged)
// ============================================================================
__global__ void k_hist(const int* __restrict__ inds1_q, int* __restrict__ bh) {
    int tid = threadIdx.x;
    int n = blockIdx.x * 256 + tid;
    int key = inds1_q[n];
    int lane = tid & 63;
    int cnt = 0;
    for (int k = 0; k < 32; ++k) {
        unsigned long long m = __ballot(key == k);
        if (lane == k) cnt = __popcll(m);
    }
    if (lane < 32) bh[(n >> 6) * 32 + lane] = cnt;
}

// ============================================================================
// k_scanA: 32 blocks (class each); scan 768 seg counts -> ebb, total[k]
// ============================================================================
__global__ void k_scanA(const int* __restrict__ bh, int* __restrict__ ebb,
                        int* __restrict__ total) {
    __shared__ int s[256];
    const int k = blockIdx.x, t = threadIdx.x;
    int v0 = bh[(t * 3 + 0) * 32 + k];
    int v1 = bh[(t * 3 + 1) * 32 + k];
    int v2 = bh[(t * 3 + 2) * 32 + k];
    int sum = v0 + v1 + v2;
    s[t] = sum; __syncthreads();
    for (int d = 1; d < 256; d <<= 1) {
        int x = (t >= d) ? s[t - d] : 0;
        __syncthreads();
        s[t] += x;
        __syncthreads();
    }
    int ex = s[t] - sum;
    ebb[(t * 3 + 0) * 32 + k] = ex;
    ebb[(t * 3 + 1) * 32 + k] = ex + v0;
    ebb[(t * 3 + 2) * 32 + k] = ex + v0 + v1;
    if (t == 255) total[k] = s[255];
}

// ============================================================================
// k_scatter2: deterministic rank scatter, local class bases (unchanged)
// ============================================================================
__global__ void k_scatter2(const int* __restrict__ inds1_q,
                           const int* __restrict__ ebb,
                           const int* __restrict__ total,
                           int* __restrict__ order)
{
    __shared__ int ttot[32];
    const int tid = threadIdx.x;
    if (tid < 32) ttot[tid] = total[tid];
    __syncthreads();
    int n = blockIdx.x * 256 + tid;
    int key = inds1_q[n];
    int lane = tid & 63;
    unsigned long long peers = 0;
    for (int k = 0; k < 32; ++k) {
        unsigned long long m = __ballot(key == k);
        if (key == k) peers = m;
    }
    int rank = __popcll(peers & ((1ull << lane) - 1ull));
    int cbase = 0;
    #pragma unroll
    for (int k = 0; k < 32; ++k) cbase += (k < key) ? ttot[k] : 0;
    order[cbase + ebb[(n >> 6) * 32 + key] + rank] = n;
}

// ============================================================================
// k2h: stage-2 first half (exact R0 baseline)
// ============================================================================
__global__ __launch_bounds__(256, 4) void k2h(
    const float* __restrict__ x_t,
    const float* __restrict__ Wcl22, const float* __restrict__ bcl22,
    const float* __restrict__ Wcl32, const float* __restrict__ bcl32,
    const int* __restrict__ total, const int* __restrict__ order,
    int* __restrict__ ind_ord)
{
    __shared__ float Was[4096];
    __shared__ float Wbs[1024];
    __shared__ int cpre[33];
    __shared__ int cbase[33];
    __shared__ int ttot[32];

    const int tid = threadIdx.x;
    if (tid < 32) ttot[tid] = total[tid];
    __syncthreads();
    if (tid == 0) {
        int s = 0, cb = 0;
        for (int k = 0; k < 32; ++k) {
            cpre[k] = s; cbase[k] = cb;
            int c = ttot[k];
            s += (c + 255) >> 8;
            cb += c;
        }
        cpre[32] = s; cbase[32] = cb;
    }
    __syncthreads();
    const int ci = blockIdx.x;
    if (ci >= cpre[32]) return;
    int cls = 0;
    while (cpre[cls + 1] <= ci) ++cls;
    const int st   = (ci - cpre[cls]) * 256;
    const int npx  = min(256, ttot[cls] - st);
    const int base = cbase[cls] + st;

    {
        const float4* ws = (const float4*)(Wcl22 + cls * 4096);
        #pragma unroll
        for (int j = 0; j < 4; ++j) ((float4*)Was)[j * 256 + tid] = ws[j * 256 + tid];
        ((float4*)Wbs)[tid] = ((const float4*)(Wcl32 + cls * 1024))[tid];
    }
    __syncthreads();

    const int m = order[base + min(tid, npx - 1)];
    const float4* xp = (const float4*)(x_t + (size_t)m * 128);

    float h[32];
    #pragma unroll
    for (int j = 0; j < 32; ++j) h[j] = bcl22[cls * 32 + j];
    #pragma unroll 2
    for (int c4 = 0; c4 < 32; ++c4) {
        float4 xv = xp[c4];
        float xa[4] = {xv.x, xv.y, xv.z, xv.w};
        #pragma unroll
        for (int cc = 0; cc < 4; ++cc) {
            const float* wr = &Was[(c4 * 4 + cc) * 32];
            #pragma unroll
            for (int j = 0; j < 32; ++j) h[j] = fmaf(xa[cc], wr[j], h[j]);
        }
    }
    #pragma unroll
    for (int j = 0; j < 32; ++j) h[j] = lrelu(h[j]);

    float g[32];
    #pragma unroll
    for (int j = 0; j < 32; ++j) g[j] = bcl32[cls * 32 + j];
    #pragma unroll 2
    for (int c = 0; c < 32; ++c) {
        float hv = h[c];
        const float* wr = &Wbs[c * 32];
        #pragma unroll
        for (int j = 0; j < 32; ++j) g[j] = fmaf(hv, wr[j], g[j]);
    }
    float bv = g[0]; int bi = 0;
    #pragma unroll
    for (int j = 1; j < 32; ++j)
        if (g[j] > bv) { bv = g[j]; bi = j; }     // strict > = first-max (np.argmax)
    if (tid < npx) ind_ord[base + tid] = cls * 32 + bi;
}

// ============================================================================
// k2r: stage-2 second half (exact R0 baseline)
// ============================================================================
__global__ __launch_bounds__(256, 4) void k2r(
    const float* __restrict__ r_t,
    const float* __restrict__ Wr2,  const float* __restrict__ br2,
    const float* __restrict__ Wr3,  const float* __restrict__ br3,
    const int* __restrict__ total, const int* __restrict__ order,
    const int* __restrict__ ind_ord,
    float* __restrict__ out)
{
    __shared__ float Wcs[4096];
    __shared__ int cpre[33];
    __shared__ int cbase[33];
    __shared__ int ttot[32];

    const int tid = threadIdx.x;
    if (tid < 32) ttot[tid] = total[tid];
    __syncthreads();
    if (tid == 0) {
        int s = 0, cb = 0;
        for (int k = 0; k < 32; ++k) {
            cpre[k] = s; cbase[k] = cb;
            int c = ttot[k];
            s += (c + 255) >> 8;
            cb += c;
        }
        cpre[32] = s; cbase[32] = cb;
    }
    __syncthreads();
    const int ci = blockIdx.x;
    if (ci >= cpre[32]) return;
    int cls = 0;
    while (cpre[cls + 1] <= ci) ++cls;
    const int st   = (ci - cpre[cls]) * 256;
    const int npx  = min(256, ttot[cls] - st);
    const int base = cbase[cls] + st;
    const int sup  = cls >> 2;

    {
        const float4* ws = (const float4*)(Wr2 + sup * 4096);
        #pragma unroll
        for (int j = 0; j < 4; ++j) ((float4*)Wcs)[j * 256 + tid] = ws[j * 256 + tid];
    }
    __syncthreads();

    const int li  = min(tid, npx - 1);
    const int m   = order[base + li];
    const int ind = ind_ord[base + li];
    const float4* rp = (const float4*)(r_t + (size_t)m * 128);

    float r2[32];
    #pragma unroll
    for (int j = 0; j < 32; ++j) r2[j] = br2[sup * 32 + j];
    #pragma unroll 2
    for (int c4 = 0; c4 < 32; ++c4) {
        float4 rv = rp[c4];
        float ra[4] = {rv.x, rv.y, rv.z, rv.w};
        #pragma unroll
        for (int cc = 0; cc < 4; ++cc) {
            const float* wr = &Wcs[(c4 * 4 + cc) * 32];
            #pragma unroll
            for (int j = 0; j < 32; ++j) r2[j] = fmaf(ra[cc], wr[j], r2[j]);
        }
    }

    float reg = br3[ind];
    const float* __restrict__ w3 = Wr3 + ind * 32;
    #pragma unroll
    for (int j = 0; j < 32; ++j) reg = fmaf(lrelu(r2[j]), w3[j], reg);

    if (tid < npx) out[m] = ((float)ind + reg) * (1.0f / 1024.0f);
}

extern "C" void kernel_launch(void* const* d_in, const int* in_sizes, int n_in,
                              void* d_out, int out_size, void* d_ws, size_t ws_size,
                              hipStream_t stream)
{
    const float* X     = (const float*)d_in[0];
    const float* Wm1   = (const float*)d_in[1];
    const float* bm1   = (const float*)d_in[2];
    const float* Wm2   = (const float*)d_in[3];
    const float* bm2   = (const float*)d_in[4];
    const float* Wm3   = (const float*)d_in[5];
    const float* bm3   = (const float*)d_in[6];
    const float* Wcl1  = (const float*)d_in[7];
    const float* bcl1  = (const float*)d_in[8];
    const float* Wcl21 = (const float*)d_in[9];
    const float* bcl21 = (const float*)d_in[10];
    const float* Wcl31 = (const float*)d_in[11];
    const float* bcl31 = (const float*)d_in[12];
    const float* Wcl22 = (const float*)d_in[13];
    const float* bcl22 = (const float*)d_in[14];
    const float* Wcl32 = (const float*)d_in[15];
    const float* bcl32 = (const float*)d_in[16];
    const float* Wr1   = (const float*)d_in[17];
    const float* br1   = (const float*)d_in[18];
    const float* Wr2   = (const float*)d_in[19];
    const float* br2   = (const float*)d_in[20];
    const float* Wr3   = (const float*)d_in[21];
    const float* br3   = (const float*)d_in[22];
    float* out = (float*)d_out;

    float* x_t   = (float*)d_ws;
    float* r_t   = x_t + (size_t)NPIX * 128;
    int* inds1_q = (int*)(r_t + (size_t)NPIX * 128);
    int* order   = inds1_q + NPIX;
    int* ind_ord = order + NPIX;
    int* bh      = ind_ord + NPIX;      // [768][32]
    int* ebb     = bh + NSEG * 32;      // [768][32]
    int* total   = ebb + NSEG * 32;     // [32]
    // R12: transposed weights ALIAS bh/ebb (147KB < 196KB). Lifetime-safe:
    // k_tw writes -> k_fused1 reads -> (later) k_hist/k_scanA overwrite.
    float* Wct   = (float*)bh;             // [128][128] transposed Wcl1
    float* Wrt   = Wct + 16384;            // [128][128] transposed Wr1
    float* Wmt   = Wrt + 16384;            // [128][32]  transposed Wm1

    k_tw<<<3, 256, 0, stream>>>(Wcl1, Wr1, Wm1, Wct, Wrt, Wmt);
    k_fused1<<<dim3(NPIX / 128, 3), 256, 0, stream>>>(X, Wct, bcl1, Wrt, br1,
                                                      Wmt, bm1, Wm2, bm2, Wm3, bm3,
                                                      x_t, r_t, out);
    k1b<<<NPIX / 128, 256, 0, stream>>>(x_t, Wcl21, bcl21, Wcl31, bcl31, inds1_q);
    k_hist<<<NPIX / 256, 256, 0, stream>>>(inds1_q, bh);
    k_scanA<<<32, 256, 0, stream>>>(bh, ebb, total);
    k_scatter2<<<NPIX / 256, 256, 0, stream>>>(inds1_q, ebb, total, order);
    // 256-px chunks: worst case sum ceil = 192 + 31 = 223 -> grid 224 covers all
    k2h<<<224, 256, 0, stream>>>(x_t, Wcl22, bcl22, Wcl32, bcl32, total, order, ind_ord);
    k2r<<<224, 256, 0, stream>>>(r_t, Wr2, br2, Wr3, br3, total, order, ind_ord, out);
}

// Round 7
// 255.313 us; speedup vs baseline: 2.0121x; 2.0121x over previous
//
#include <hip/hip_runtime.h>

#define HH 192
#define WW 256
#define NPIX (HH*WW)   // 49152
#define NSEG (NPIX/64) // 768

__device__ __forceinline__ float lrelu(float v) { return v > 0.0f ? v : 0.01f * v; }

// ============================================================================
// k_fused1 (R13): R6 single-buffered structure with K-tile 32 (was 16).
// Half the barriers, 2x FMA per exposed-latency window. Codegen pinned to the
// known-good shape: plain loads -> LDS -> barrier -> compute -> barrier;
// compute split 2 x unroll-16 with outer '#pragma unroll 1' so the body size
// matches R6's (the regime where acc[8][8] stays in registers).
// SPILL LEDGER (all showed FETCH/WRITE ballooning + VALUBusy collapse):
//   R7  reg-prefetch + runtime LDS ptr swap  -> 670us
//   R12 global_load_lds 2-phase (auto-unrolled x4) -> 313us
//   R10 bounds-4 (reg-starved staging)       -> 62us
// Do not restructure the inner loop away from this shape.
// ============================================================================
__global__ __launch_bounds__(256, 3) void k_fused1(
    const float* __restrict__ X,
    const float* __restrict__ Wcl1, const float* __restrict__ bcl1,
    const float* __restrict__ Wr1,  const float* __restrict__ br1,
    const float* __restrict__ Wm1,  const float* __restrict__ bm1,
    const float* __restrict__ Wm2,  const float* __restrict__ bm2,
    const float* __restrict__ Wm3,  const float* __restrict__ bm3,
    float* __restrict__ x_t, float* __restrict__ r_t,
    float* __restrict__ out)
{
    __shared__ float smem[8448];                      // 33792 B
    float (*As)[132]   = (float(*)[132])smem;         // [32][132]
    float (*Ws)[132]   = (float(*)[132])(smem + 4224);// [32][132]
    float (*m1buf)[33] = (float(*)[33])smem;          // y=2 epilogue; aliases As

    const int tid = threadIdx.x;
    const int q0  = blockIdx.x * 128;

    if (blockIdx.y == 2) {
        const int tc = tid & 31;
        const int tr = tid >> 5;
        float acc[4][4];
        #pragma unroll
        for (int i = 0; i < 4; ++i)
            #pragma unroll
            for (int j = 0; j < 4; ++j)
                acc[i][j] = bm1[tr * 4 + j];

        for (int k0 = 0; k0 < 128; k0 += 32) {
            #pragma unroll
            for (int p = 0; p < 4; ++p) {
                int lin = p * 1024 + tid * 4;
                int kk = lin >> 7, px = lin & 127;
                float4 v = *(const float4*)(X + (size_t)(k0 + kk) * NPIX + q0 + px);
                *(float4*)(&As[kk][px]) = v;
            }
            {
                int row = tid >> 3, kc = (tid & 7) * 4;   // 32 rows x 8 kc-groups
                float4 v = *(const float4*)(Wm1 + row * 128 + k0 + kc);
                Ws[kc + 0][row] = v.x; Ws[kc + 1][row] = v.y;
                Ws[kc + 2][row] = v.z; Ws[kc + 3][row] = v.w;
            }
            __syncthreads();
            #pragma unroll 1
            for (int kh = 0; kh < 2; ++kh) {
                #pragma unroll
                for (int kq = 0; kq < 16; ++kq) {
                    int kk = kh * 16 + kq;
                    float4 a = *(const float4*)(&As[kk][tc * 4]);
                    float4 w = *(const float4*)(&Ws[kk][tr * 4]);
                    float av[4] = {a.x,a.y,a.z,a.w};
                    float wv[4] = {w.x,w.y,w.z,w.w};
                    #pragma unroll
                    for (int i = 0; i < 4; ++i)
                        #pragma unroll
                        for (int j = 0; j < 4; ++j)
                            acc[i][j] = fmaf(av[i], wv[j], acc[i][j]);
                }
            }
            __syncthreads();
        }
        // loop ends with a barrier -> safe to overwrite aliased As with m1buf
        #pragma unroll
        for (int i = 0; i < 4; ++i)
            #pragma unroll
            for (int j = 0; j < 4; ++j)
                m1buf[tc * 4 + i][tr * 4 + j] = lrelu(acc[i][j]);
        __syncthreads();
        if (tid < 128) {
            float m3 = bm3[0];
            #pragma unroll 2
            for (int j = 0; j < 16; ++j) {
                float s = bm2[j];
                #pragma unroll
                for (int k = 0; k < 32; ++k)
                    s = fmaf(Wm2[j * 32 + k], m1buf[tid][k], s);
                m3 = fmaf(Wm3[j], lrelu(s), m3);
            }
            out[NPIX + q0 + tid] = lrelu(m3);
        }
        return;
    }

    const float* __restrict__ W    = (blockIdx.y == 0) ? Wcl1 : Wr1;
    const float* __restrict__ bias = (blockIdx.y == 0) ? bcl1 : br1;
    float* __restrict__ outp       = (blockIdx.y == 0) ? x_t : r_t;

    const int tc = tid & 15;
    const int tr = tid >> 4;

    float acc[8][8];
    #pragma unroll
    for (int i = 0; i < 8; ++i)
        #pragma unroll
        for (int j = 0; j < 8; ++j)
            acc[i][j] = bias[(j >> 2) * 64 + tr * 4 + (j & 3)];

    for (int k0 = 0; k0 < 128; k0 += 32) {
        #pragma unroll
        for (int p = 0; p < 4; ++p) {
            int lin = p * 1024 + tid * 4;
            int kk = lin >> 7, px = lin & 127;
            float4 v = *(const float4*)(X + (size_t)(k0 + kk) * NPIX + q0 + px);
            *(float4*)(&As[kk][px]) = v;
        }
        #pragma unroll
        for (int p = 0; p < 4; ++p) {
            int lin = p * 256 + tid;              // float4 index
            int row = lin >> 3, kc = (lin & 7) * 4;  // 128 rows x 8 kc-groups
            float4 v = *(const float4*)(W + row * 128 + k0 + kc);
            Ws[kc + 0][row] = v.x; Ws[kc + 1][row] = v.y;
            Ws[kc + 2][row] = v.z; Ws[kc + 3][row] = v.w;
        }
        __syncthreads();
        #pragma unroll 1
        for (int kh = 0; kh < 2; ++kh) {
            #pragma unroll
            for (int kq = 0; kq < 16; ++kq) {
                int kk = kh * 16 + kq;
                float4 a0 = *(const float4*)(&As[kk][tc * 4]);
                float4 a1 = *(const float4*)(&As[kk][64 + tc * 4]);
                float4 w0 = *(const float4*)(&Ws[kk][tr * 4]);
                float4 w1 = *(const float4*)(&Ws[kk][64 + tr * 4]);
                float av[8] = {a0.x,a0.y,a0.z,a0.w,a1.x,a1.y,a1.z,a1.w};
                float wv[8] = {w0.x,w0.y,w0.z,w0.w,w1.x,w1.y,w1.z,w1.w};
                #pragma unroll
                for (int i = 0; i < 8; ++i)
                    #pragma unroll
                    for (int j = 0; j < 8; ++j)
                        acc[i][j] = fmaf(av[i], wv[j], acc[i][j]);
            }
        }
        __syncthreads();
    }

    #pragma unroll
    for (int i = 0; i < 8; ++i) {
        int px = (i >> 2) * 64 + tc * 4 + (i & 3);
        int q  = q0 + px;
        int np = (q & 255) * 192 + (q >> 8);
        float* op = outp + (size_t)np * 128;
        #pragma unroll
        for (int jg = 0; jg < 2; ++jg) {
            float4 o;
            o.x = lrelu(acc[i][jg*4+0]); o.y = lrelu(acc[i][jg*4+1]);
            o.z = lrelu(acc[i][jg*4+2]); o.w = lrelu(acc[i][jg*4+3]);
            *(float4*)(op + jg * 64 + tr * 4) = o;
        }
    }
}

// ============================================================================
// k1b: x2 = lrelu(Wcl21@x), cl1 = Wcl31@x2 + argmax -> inds1_q (q-order).
// (exact R0 text)
// ============================================================================
__global__ __launch_bounds__(256, 2) void k1b(
    const float* __restrict__ x_t,
    const float* __restrict__ Wcl21, const float* __restrict__ bcl21,
    const float* __restrict__ Wcl31, const float* __restrict__ bcl31,
    int* __restrict__ inds1_q)
{
    __shared__ float smem[12672];
    float (*As)[132]     = (float(*)[132])smem;
    float (*Ws)[132]     = (float(*)[132])(smem + 2112);
    float (*W31)[132]    = (float(*)[132])smem;
    float (*x2t)[132]    = (float(*)[132])(smem + 4224);
    float (*cl1buf)[33]  = (float(*)[33]) (smem + 4224);

    const int tid = threadIdx.x;
    const int n0  = blockIdx.x * 128;
    const int tcA = tid & 15, trA = tid >> 4;
    const int tcB = tid & 31, trB = tid >> 5;

    float accB[4][4];
    #pragma unroll
    for (int i = 0; i < 4; ++i)
        #pragma unroll
        for (int j = 0; j < 4; ++j)
            accB[i][j] = bcl31[trB * 4 + j];

    for (int h = 0; h < 2; ++h) {
        float acc2[2][4][4];
        #pragma unroll
        for (int gi = 0; gi < 2; ++gi)
            #pragma unroll
            for (int i = 0; i < 4; ++i)
                #pragma unroll
                for (int j = 0; j < 4; ++j)
                    acc2[gi][i][j] = bcl21[h * 64 + trA * 4 + j];

        for (int k0 = 0; k0 < 128; k0 += 16) {
            #pragma unroll
            for (int p = 0; p < 2; ++p) {
                int lin = p * 1024 + tid * 4;
                int px = lin >> 4, kc = lin & 15;
                float4 v = *(const float4*)(x_t + (size_t)(n0 + px) * 128 + k0 + kc);
                As[kc + 0][px] = v.x; As[kc + 1][px] = v.y;
                As[kc + 2][px] = v.z; As[kc + 3][px] = v.w;
            }
            {
                int r = tid >> 2, kc = (tid & 3) * 4;
                float4 v = *(const float4*)(Wcl21 + (h * 64 + r) * 128 + k0 + kc);
                Ws[kc + 0][r] = v.x; Ws[kc + 1][r] = v.y;
                Ws[kc + 2][r] = v.z; Ws[kc + 3][r] = v.w;
            }
            __syncthreads();
            #pragma unroll
            for (int kk = 0; kk < 16; ++kk) {
                float4 a0 = *(const float4*)(&As[kk][tcA * 4]);
                float4 a1 = *(const float4*)(&As[kk][64 + tcA * 4]);
                float4 w  = *(const float4*)(&Ws[kk][trA * 4]);
                float av0[4] = {a0.x,a0.y,a0.z,a0.w};
                float av1[4] = {a1.x,a1.y,a1.z,a1.w};
                float wv[4]  = {w.x,w.y,w.z,w.w};
                #pragma unroll
                for (int i = 0; i < 4; ++i)
                    #pragma unroll
                    for (int j = 0; j < 4; ++j) {
                        acc2[0][i][j] = fmaf(av0[i], wv[j], acc2[0][i][j]);
                        acc2[1][i][j] = fmaf(av1[i], wv[j], acc2[1][i][j]);
                    }
            }
            __syncthreads();
        }
        #pragma unroll
        for (int j = 0; j < 4; ++j) {
            int row = trA * 4 + j;
            #pragma unroll
            for (int gi = 0; gi < 2; ++gi) {
                float4 o;
                o.x = lrelu(acc2[gi][0][j]); o.y = lrelu(acc2[gi][1][j]);
                o.z = lrelu(acc2[gi][2][j]); o.w = lrelu(acc2[gi][3][j]);
                *(float4*)(&x2t[row][gi * 64 + tcA * 4]) = o;
            }
        }
        __syncthreads();
        #pragma unroll
        for (int p = 0; p < 4; ++p) {
            int lin = p * 1024 + tid * 4;
            int row = lin >> 7, kc = lin & 127;
            *(float4*)(&W31[row][kc]) = *(const float4*)(Wcl31 + row * 128 + kc);
        }
        __syncthreads();
        for (int k = 0; k < 64; ++k) {
            float4 a = *(const float4*)(&x2t[k][tcB * 4]);
            float av[4] = {a.x,a.y,a.z,a.w};
            float wv[4];
            #pragma unroll
            for (int j = 0; j < 4; ++j) wv[j] = W31[trB * 4 + j][h * 64 + k];
            #pragma unroll
            for (int i = 0; i < 4; ++i)
                #pragma unroll
                for (int j = 0; j < 4; ++j)
                    accB[i][j] = fmaf(av[i], wv[j], accB[i][j]);
        }
        __syncthreads();
    }

    #pragma unroll
    for (int i = 0; i < 4; ++i)
        #pragma unroll
        for (int j = 0; j < 4; ++j)
            cl1buf[tcB * 4 + i][trB * 4 + j] = accB[i][j];
    __syncthreads();
    if (tid < 128) {
        float bv = cl1buf[tid][0]; int bi = 0;
        #pragma unroll
        for (int c = 1; c < 32; ++c) {
            float v = cl1buf[tid][c];
            if (v > bv) { bv = v; bi = c; }
        }
        int n = n0 + tid;
        int w = n / 192, hh = n - w * 192;
        inds1_q[hh * 256 + w] = bi;
    }
}

// ============================================================================
// k_hist: 192 blocks; per-64-seg ballot histogram -> bh[seg][32] (unchanged)
// ============================================================================
__global__ void k_hist(const int* __restrict__ inds1_q, int* __restrict__ bh) {
    int tid = threadIdx.x;
    int n = blockIdx.x * 256 + tid;
    int key = inds1_q[n];
    int lane = tid & 63;
    int cnt = 0;
    for (int k = 0; k < 32; ++k) {
        unsigned long long m = __ballot(key == k);
        if (lane == k) cnt = __popcll(m);
    }
    if (lane < 32) bh[(n >> 6) * 32 + lane] = cnt;
}

// ============================================================================
// k_scanA: 32 blocks (class each); scan 768 seg counts -> ebb, total[k]
// ============================================================================
__global__ void k_scanA(const int* __restrict__ bh, int* __restrict__ ebb,
                        int* __restrict__ total) {
    __shared__ int s[256];
    const int k = blockIdx.x, t = threadIdx.x;
    int v0 = bh[(t * 3 + 0) * 32 + k];
    int v1 = bh[(t * 3 + 1) * 32 + k];
    int v2 = bh[(t * 3 + 2) * 32 + k];
    int sum = v0 + v1 + v2;
    s[t] = sum; __syncthreads();
    for (int d = 1; d < 256; d <<= 1) {
        int x = (t >= d) ? s[t - d] : 0;
        __syncthreads();
        s[t] += x;
        __syncthreads();
    }
    int ex = s[t] - sum;
    ebb[(t * 3 + 0) * 32 + k] = ex;
    ebb[(t * 3 + 1) * 32 + k] = ex + v0;
    ebb[(t * 3 + 2) * 32 + k] = ex + v0 + v1;
    if (t == 255) total[k] = s[255];
}

// ============================================================================
// k_scatter2: deterministic rank scatter, local class bases (unchanged)
// ============================================================================
__global__ void k_scatter2(const int* __restrict__ inds1_q,
                           const int* __restrict__ ebb,
                           const int* __restrict__ total,
                           int* __restrict__ order)
{
    __shared__ int ttot[32];
    const int tid = threadIdx.x;
    if (tid < 32) ttot[tid] = total[tid];
    __syncthreads();
    int n = blockIdx.x * 256 + tid;
    int key = inds1_q[n];
    int lane = tid & 63;
    unsigned long long peers = 0;
    for (int k = 0; k < 32; ++k) {
        unsigned long long m = __ballot(key == k);
        if (key == k) peers = m;
    }
    int rank = __popcll(peers & ((1ull << lane) - 1ull));
    int cbase = 0;
    #pragma unroll
    for (int k = 0; k < 32; ++k) cbase += (k < key) ? ttot[k] : 0;
    order[cbase + ebb[(n >> 6) * 32 + key] + rank] = n;
}

// ============================================================================
// k2h: stage-2 first half (exact R0 baseline)
// ============================================================================
__global__ __launch_bounds__(256, 4) void k2h(
    const float* __restrict__ x_t,
    const float* __restrict__ Wcl22, const float* __restrict__ bcl22,
    const float* __restrict__ Wcl32, const float* __restrict__ bcl32,
    const int* __restrict__ total, const int* __restrict__ order,
    int* __restrict__ ind_ord)
{
    __shared__ float Was[4096];
    __shared__ float Wbs[1024];
    __shared__ int cpre[33];
    __shared__ int cbase[33];
    __shared__ int ttot[32];

    const int tid = threadIdx.x;
    if (tid < 32) ttot[tid] = total[tid];
    __syncthreads();
    if (tid == 0) {
        int s = 0, cb = 0;
        for (int k = 0; k < 32; ++k) {
            cpre[k] = s; cbase[k] = cb;
            int c = ttot[k];
            s += (c + 255) >> 8;
            cb += c;
        }
        cpre[32] = s; cbase[32] = cb;
    }
    __syncthreads();
    const int ci = blockIdx.x;
    if (ci >= cpre[32]) return;
    int cls = 0;
    while (cpre[cls + 1] <= ci) ++cls;
    const int st   = (ci - cpre[cls]) * 256;
    const int npx  = min(256, ttot[cls] - st);
    const int base = cbase[cls] + st;

    {
        const float4* ws = (const float4*)(Wcl22 + cls * 4096);
        #pragma unroll
        for (int j = 0; j < 4; ++j) ((float4*)Was)[j * 256 + tid] = ws[j * 256 + tid];
        ((float4*)Wbs)[tid] = ((const float4*)(Wcl32 + cls * 1024))[tid];
    }
    __syncthreads();

    const int m = order[base + min(tid, npx - 1)];
    const float4* xp = (const float4*)(x_t + (size_t)m * 128);

    float h[32];
    #pragma unroll
    for (int j = 0; j < 32; ++j) h[j] = bcl22[cls * 32 + j];
    #pragma unroll 2
    for (int c4 = 0; c4 < 32; ++c4) {
        float4 xv = xp[c4];
        float xa[4] = {xv.x, xv.y, xv.z, xv.w};
        #pragma unroll
        for (int cc = 0; cc < 4; ++cc) {
            const float* wr = &Was[(c4 * 4 + cc) * 32];
            #pragma unroll
            for (int j = 0; j < 32; ++j) h[j] = fmaf(xa[cc], wr[j], h[j]);
        }
    }
    #pragma unroll
    for (int j = 0; j < 32; ++j) h[j] = lrelu(h[j]);

    float g[32];
    #pragma unroll
    for (int j = 0; j < 32; ++j) g[j] = bcl32[cls * 32 + j];
    #pragma unroll 2
    for (int c = 0; c < 32; ++c) {
        float hv = h[c];
        const float* wr = &Wbs[c * 32];
        #pragma unroll
        for (int j = 0; j < 32; ++j) g[j] = fmaf(hv, wr[j], g[j]);
    }
    float bv = g[0]; int bi = 0;
    #pragma unroll
    for (int j = 1; j < 32; ++j)
        if (g[j] > bv) { bv = g[j]; bi = j; }     // strict > = first-max (np.argmax)
    if (tid < npx) ind_ord[base + tid] = cls * 32 + bi;
}

// ============================================================================
// k2r: stage-2 second half (exact R0 baseline)
// ============================================================================
__global__ __launch_bounds__(256, 4) void k2r(
    const float* __restrict__ r_t,
    const float* __restrict__ Wr2,  const float* __restrict__ br2,
    const float* __restrict__ Wr3,  const float* __restrict__ br3,
    const int* __restrict__ total, const int* __restrict__ order,
    const int* __restrict__ ind_ord,
    float* __restrict__ out)
{
    __shared__ float Wcs[4096];
    __shared__ int cpre[33];
    __shared__ int cbase[33];
    __shared__ int ttot[32];

    const int tid = threadIdx.x;
    if (tid < 32) ttot[tid] = total[tid];
    __syncthreads();
    if (tid == 0) {
        int s = 0, cb = 0;
        for (int k = 0; k < 32; ++k) {
            cpre[k] = s; cbase[k] = cb;
            int c = ttot[k];
            s += (c + 255) >> 8;
            cb += c;
        }
        cpre[32] = s; cbase[32] = cb;
    }
    __syncthreads();
    const int ci = blockIdx.x;
    if (ci >= cpre[32]) return;
    int cls = 0;
    while (cpre[cls + 1] <= ci) ++cls;
    const int st   = (ci - cpre[cls]) * 256;
    const int npx  = min(256, ttot[cls] - st);
    const int base = cbase[cls] + st;
    const int sup  = cls >> 2;

    {
        const float4* ws = (const float4*)(Wr2 + sup * 4096);
        #pragma unroll
        for (int j = 0; j < 4; ++j) ((float4*)Wcs)[j * 256 + tid] = ws[j * 256 + tid];
    }
    __syncthreads();

    const int li  = min(tid, npx - 1);
    const int m   = order[base + li];
    const int ind = ind_ord[base + li];
    const float4* rp = (const float4*)(r_t + (size_t)m * 128);

    float r2[32];
    #pragma unroll
    for (int j = 0; j < 32; ++j) r2[j] = br2[sup * 32 + j];
    #pragma unroll 2
    for (int c4 = 0; c4 < 32; ++c4) {
        float4 rv = rp[c4];
        float ra[4] = {rv.x, rv.y, rv.z, rv.w};
        #pragma unroll
        for (int cc = 0; cc < 4; ++cc) {
            const float* wr = &Wcs[(c4 * 4 + cc) * 32];
            #pragma unroll
            for (int j = 0; j < 32; ++j) r2[j] = fmaf(ra[cc], wr[j], r2[j]);
        }
    }

    float reg = br3[ind];
    const float* __restrict__ w3 = Wr3 + ind * 32;
    #pragma unroll
    for (int j = 0; j < 32; ++j) reg = fmaf(lrelu(r2[j]), w3[j], reg);

    if (tid < npx) out[m] = ((float)ind + reg) * (1.0f / 1024.0f);
}

extern "C" void kernel_launch(void* const* d_in, const int* in_sizes, int n_in,
                              void* d_out, int out_size, void* d_ws, size_t ws_size,
                              hipStream_t stream)
{
    const float* X     = (const float*)d_in[0];
    const float* Wm1   = (const float*)d_in[1];
    const float* bm1   = (const float*)d_in[2];
    const float* Wm2   = (const float*)d_in[3];
    const float* bm2   = (const float*)d_in[4];
    const float* Wm3   = (const float*)d_in[5];
    const float* bm3   = (const float*)d_in[6];
    const float* Wcl1  = (const float*)d_in[7];
    const float* bcl1  = (const float*)d_in[8];
    const float* Wcl21 = (const float*)d_in[9];
    const float* bcl21 = (const float*)d_in[10];
    const float* Wcl31 = (const float*)d_in[11];
    const float* bcl31 = (const float*)d_in[12];
    const float* Wcl22 = (const float*)d_in[13];
    const float* bcl22 = (const float*)d_in[14];
    const float* Wcl32 = (const float*)d_in[15];
    const float* bcl32 = (const float*)d_in[16];
    const float* Wr1   = (const float*)d_in[17];
    const float* br1   = (const float*)d_in[18];
    const float* Wr2   = (const float*)d_in[19];
    const float* br2   = (const float*)d_in[20];
    const float* Wr3   = (const float*)d_in[21];
    const float* br3   = (const float*)d_in[22];
    float* out = (float*)d_out;

    float* x_t   = (float*)d_ws;
    float* r_t   = x_t + (size_t)NPIX * 128;
    int* inds1_q = (int*)(r_t + (size_t)NPIX * 128);
    int* order   = inds1_q + NPIX;
    int* ind_ord = order + NPIX;
    int* bh      = ind_ord + NPIX;      // [768][32]
    int* ebb     = bh + NSEG * 32;      // [768][32]
    int* total   = ebb + NSEG * 32;     // [32]

    k_fused1<<<dim3(NPIX / 128, 3), 256, 0, stream>>>(X, Wcl1, bcl1, Wr1, br1,
                                                      Wm1, bm1, Wm2, bm2, Wm3, bm3,
                                                      x_t, r_t, out);
    k1b<<<NPIX / 128, 256, 0, stream>>>(x_t, Wcl21, bcl21, Wcl31, bcl31, inds1_q);
    k_hist<<<NPIX / 256, 256, 0, stream>>>(inds1_q, bh);
    k_scanA<<<32, 256, 0, stream>>>(bh, ebb, total);
    k_scatter2<<<NPIX / 256, 256, 0, stream>>>(inds1_q, ebb, total, order);
    // 256-px chunks: worst case sum ceil = 192 + 31 = 223 -> grid 224 covers all
    k2h<<<224, 256, 0, stream>>>(x_t, Wcl22, bcl22, Wcl32, bcl32, total, order, ind_ord);
    k2r<<<224, 256, 0, stream>>>(r_t, Wr2, br2, Wr3, br3, total, order, ind_ord, out);
}

// Round 8
// 241.870 us; speedup vs baseline: 2.1240x; 1.0556x over previous
//
#include <hip/hip_runtime.h>

#define HH 192
#define WW 256
#define NPIX (HH*WW)   // 49152
#define NSEG (NPIX/64) // 768

__device__ __forceinline__ float lrelu(float v) { return v > 0.0f ? v : 0.01f * v; }

// ============================================================================
// k_fused1: EXACT R6 text (57us, 72 VGPR, 48% VALUBusy). CLOSED after 6
// failed structural attempts:
//   R7  reg-prefetch dbuf      -> acc spill, 670us
//   R9  mask-fusion            -> critical-path imbalance, 62us
//   R10 bounds-4               -> reg-starved staging, 62us
//   R12 global_load_lds 2phase -> acc spill, 313us
//   R13 BK=32                  -> 2.7x bank conflicts, 61us
// Issue floor ~23us; stall is barrier-drain structural; allocator blocks
// every pipelining route. Do not touch.
// ============================================================================
__global__ __launch_bounds__(256, 3) void k_fused1(
    const float* __restrict__ X,
    const float* __restrict__ Wcl1, const float* __restrict__ bcl1,
    const float* __restrict__ Wr1,  const float* __restrict__ br1,
    const float* __restrict__ Wm1,  const float* __restrict__ bm1,
    const float* __restrict__ Wm2,  const float* __restrict__ bm2,
    const float* __restrict__ Wm3,  const float* __restrict__ bm3,
    float* __restrict__ x_t, float* __restrict__ r_t,
    float* __restrict__ out)
{
    __shared__ float As[16][132];
    __shared__ float Ws[16][132];
    __shared__ float m1buf[128][33];
    const int tid = threadIdx.x;
    const int q0  = blockIdx.x * 128;

    if (blockIdx.y == 2) {
        const int tc = tid & 31;
        const int tr = tid >> 5;
        float acc[4][4];
        #pragma unroll
        for (int i = 0; i < 4; ++i)
            #pragma unroll
            for (int j = 0; j < 4; ++j)
                acc[i][j] = bm1[tr * 4 + j];

        for (int k0 = 0; k0 < 128; k0 += 16) {
            #pragma unroll
            for (int p = 0; p < 2; ++p) {
                int lin = p * 1024 + tid * 4;
                int kk = lin >> 7, px = lin & 127;
                float4 v = *(const float4*)(X + (k0 + kk) * NPIX + q0 + px);
                *(float4*)(&As[kk][px]) = v;
            }
            if (tid < 128) {
                int row = tid >> 2, kc = (tid & 3) * 4;
                float4 v = *(const float4*)(Wm1 + row * 128 + k0 + kc);
                Ws[kc + 0][row] = v.x; Ws[kc + 1][row] = v.y;
                Ws[kc + 2][row] = v.z; Ws[kc + 3][row] = v.w;
            }
            __syncthreads();
            #pragma unroll
            for (int kk = 0; kk < 16; ++kk) {
                float4 a = *(const float4*)(&As[kk][tc * 4]);
                float4 w = *(const float4*)(&Ws[kk][tr * 4]);
                float av[4] = {a.x,a.y,a.z,a.w};
                float wv[4] = {w.x,w.y,w.z,w.w};
                #pragma unroll
                for (int i = 0; i < 4; ++i)
                    #pragma unroll
                    for (int j = 0; j < 4; ++j)
                        acc[i][j] = fmaf(av[i], wv[j], acc[i][j]);
            }
            __syncthreads();
        }
        #pragma unroll
        for (int i = 0; i < 4; ++i)
            #pragma unroll
            for (int j = 0; j < 4; ++j)
                m1buf[tc * 4 + i][tr * 4 + j] = lrelu(acc[i][j]);
        __syncthreads();
        if (tid < 128) {
            float m3 = bm3[0];
            #pragma unroll 2
            for (int j = 0; j < 16; ++j) {
                float s = bm2[j];
                #pragma unroll
                for (int k = 0; k < 32; ++k)
                    s = fmaf(Wm2[j * 32 + k], m1buf[tid][k], s);
                m3 = fmaf(Wm3[j], lrelu(s), m3);
            }
            out[NPIX + q0 + tid] = lrelu(m3);
        }
        return;
    }

    const float* __restrict__ W    = (blockIdx.y == 0) ? Wcl1 : Wr1;
    const float* __restrict__ bias = (blockIdx.y == 0) ? bcl1 : br1;
    float* __restrict__ outp       = (blockIdx.y == 0) ? x_t : r_t;

    const int tc = tid & 15;
    const int tr = tid >> 4;

    float acc[8][8];
    #pragma unroll
    for (int i = 0; i < 8; ++i)
        #pragma unroll
        for (int j = 0; j < 8; ++j)
            acc[i][j] = bias[(j >> 2) * 64 + tr * 4 + (j & 3)];

    for (int k0 = 0; k0 < 128; k0 += 16) {
        #pragma unroll
        for (int p = 0; p < 2; ++p) {
            int lin = p * 1024 + tid * 4;
            int kk = lin >> 7, px = lin & 127;
            float4 v = *(const float4*)(X + (k0 + kk) * NPIX + q0 + px);
            *(float4*)(&As[kk][px]) = v;
        }
        #pragma unroll
        for (int p = 0; p < 2; ++p) {
            int lin = p * 1024 + tid * 4;
            int row = lin >> 4, kc = lin & 15;
            float4 v = *(const float4*)(W + row * 128 + k0 + kc);
            Ws[kc + 0][row] = v.x; Ws[kc + 1][row] = v.y;
            Ws[kc + 2][row] = v.z; Ws[kc + 3][row] = v.w;
        }
        __syncthreads();
        #pragma unroll
        for (int kk = 0; kk < 16; ++kk) {
            float4 a0 = *(const float4*)(&As[kk][tc * 4]);
            float4 a1 = *(const float4*)(&As[kk][64 + tc * 4]);
            float4 w0 = *(const float4*)(&Ws[kk][tr * 4]);
            float4 w1 = *(const float4*)(&Ws[kk][64 + tr * 4]);
            float av[8] = {a0.x,a0.y,a0.z,a0.w,a1.x,a1.y,a1.z,a1.w};
            float wv[8] = {w0.x,w0.y,w0.z,w0.w,w1.x,w1.y,w1.z,w1.w};
            #pragma unroll
            for (int i = 0; i < 8; ++i)
                #pragma unroll
                for (int j = 0; j < 8; ++j)
                    acc[i][j] = fmaf(av[i], wv[j], acc[i][j]);
        }
        __syncthreads();
    }

    #pragma unroll
    for (int i = 0; i < 8; ++i) {
        int px = (i >> 2) * 64 + tc * 4 + (i & 3);
        int q  = q0 + px;
        int np = (q & 255) * 192 + (q >> 8);
        float* op = outp + (size_t)np * 128;
        #pragma unroll
        for (int jg = 0; jg < 2; ++jg) {
            float4 o;
            o.x = lrelu(acc[i][jg*4+0]); o.y = lrelu(acc[i][jg*4+1]);
            o.z = lrelu(acc[i][jg*4+2]); o.w = lrelu(acc[i][jg*4+3]);
            *(float4*)(op + jg * 64 + tr * 4) = o;
        }
    }
}

// ============================================================================
// k1b (R14): h-halves MERGED. One GEMM pass over K with full 128-row Ws and
// the k_fused1-shaped acc[8][8] body (the proven no-spill regime): 8 k0-steps
// instead of 16, As staged once instead of twice, W31 staged once.
// B-phase consumes x2 in two 64-channel chunks through x2t[64][132].
// ============================================================================
__global__ __launch_bounds__(256, 2) void k1b(
    const float* __restrict__ x_t,
    const float* __restrict__ Wcl21, const float* __restrict__ bcl21,
    const float* __restrict__ Wcl31, const float* __restrict__ bcl31,
    int* __restrict__ inds1_q)
{
    __shared__ float smem[12672];
    float (*As)[132]     = (float(*)[132])smem;           // [16][132] GEMM phase
    float (*Ws)[132]     = (float(*)[132])(smem + 2112);  // [16][132] (128 rows)
    float (*W31)[132]    = (float(*)[132])smem;           // [32][132] B phase; aliases As+Ws
    float (*x2t)[132]    = (float(*)[132])(smem + 4224);  // [64][132]
    float (*cl1buf)[33]  = (float(*)[33]) (smem + 4224);  // epilogue alias

    const int tid = threadIdx.x;
    const int n0  = blockIdx.x * 128;
    const int tcA = tid & 15, trA = tid >> 4;
    const int tcB = tid & 31, trB = tid >> 5;

    // ---- merged GEMM: x2_all = lrelu(Wcl21 @ x) for all 128 out channels ----
    float acc[8][8];
    #pragma unroll
    for (int i = 0; i < 8; ++i)
        #pragma unroll
        for (int j = 0; j < 8; ++j)
            acc[i][j] = bcl21[(j >> 2) * 64 + trA * 4 + (j & 3)];

    for (int k0 = 0; k0 < 128; k0 += 16) {
        #pragma unroll
        for (int p = 0; p < 2; ++p) {
            int lin = p * 1024 + tid * 4;
            int px = lin >> 4, kc = lin & 15;
            float4 v = *(const float4*)(x_t + (size_t)(n0 + px) * 128 + k0 + kc);
            As[kc + 0][px] = v.x; As[kc + 1][px] = v.y;
            As[kc + 2][px] = v.z; As[kc + 3][px] = v.w;
        }
        #pragma unroll
        for (int p = 0; p < 2; ++p) {
            int lin = p * 256 + tid;              // float4 idx 0..511
            int r = lin >> 2, kc = (lin & 3) * 4; // 128 rows x 4 kc-groups
            float4 v = *(const float4*)(Wcl21 + r * 128 + k0 + kc);
            Ws[kc + 0][r] = v.x; Ws[kc + 1][r] = v.y;
            Ws[kc + 2][r] = v.z; Ws[kc + 3][r] = v.w;
        }
        __syncthreads();
        #pragma unroll
        for (int kk = 0; kk < 16; ++kk) {
            float4 a0 = *(const float4*)(&As[kk][tcA * 4]);
            float4 a1 = *(const float4*)(&As[kk][64 + tcA * 4]);
            float4 w0 = *(const float4*)(&Ws[kk][trA * 4]);
            float4 w1 = *(const float4*)(&Ws[kk][64 + trA * 4]);
            float av[8] = {a0.x,a0.y,a0.z,a0.w,a1.x,a1.y,a1.z,a1.w};
            float wv[8] = {w0.x,w0.y,w0.z,w0.w,w1.x,w1.y,w1.z,w1.w};
            #pragma unroll
            for (int i = 0; i < 8; ++i)
                #pragma unroll
                for (int j = 0; j < 8; ++j)
                    acc[i][j] = fmaf(av[i], wv[j], acc[i][j]);
        }
        __syncthreads();
    }

    // ---- B-phase: cl1 = Wcl31 @ x2 (+argmax), x2 fed in two 64-ch chunks ----
    float accB[4][4];
    #pragma unroll
    for (int i = 0; i < 4; ++i)
        #pragma unroll
        for (int j = 0; j < 4; ++j)
            accB[i][j] = bcl31[trB * 4 + j];

    // stage W31 once (As/Ws dead after GEMM's final barrier)
    #pragma unroll
    for (int p = 0; p < 4; ++p) {
        int lin = p * 1024 + tid * 4;
        int row = lin >> 7, kc = lin & 127;
        *(float4*)(&W31[row][kc]) = *(const float4*)(Wcl31 + row * 128 + kc);
    }
    // write x2t chunk 0 (channels 0..63): acc[.][j], j=0..3
    #pragma unroll
    for (int j = 0; j < 4; ++j) {
        int row = trA * 4 + j;
        #pragma unroll
        for (int gi = 0; gi < 2; ++gi) {
            float4 o;
            o.x = lrelu(acc[gi*4+0][j]); o.y = lrelu(acc[gi*4+1][j]);
            o.z = lrelu(acc[gi*4+2][j]); o.w = lrelu(acc[gi*4+3][j]);
            *(float4*)(&x2t[row][gi * 64 + tcA * 4]) = o;
        }
    }
    __syncthreads();
    for (int k = 0; k < 64; ++k) {
        float4 a = *(const float4*)(&x2t[k][tcB * 4]);
        float av[4] = {a.x,a.y,a.z,a.w};
        float wv[4];
        #pragma unroll
        for (int j = 0; j < 4; ++j) wv[j] = W31[trB * 4 + j][k];
        #pragma unroll
        for (int i = 0; i < 4; ++i)
            #pragma unroll
            for (int j = 0; j < 4; ++j)
                accB[i][j] = fmaf(av[i], wv[j], accB[i][j]);
    }
    __syncthreads();
    // write x2t chunk 1 (channels 64..127): acc[.][4+j]
    #pragma unroll
    for (int j = 0; j < 4; ++j) {
        int row = trA * 4 + j;
        #pragma unroll
        for (int gi = 0; gi < 2; ++gi) {
            float4 o;
            o.x = lrelu(acc[gi*4+0][4+j]); o.y = lrelu(acc[gi*4+1][4+j]);
            o.z = lrelu(acc[gi*4+2][4+j]); o.w = lrelu(acc[gi*4+3][4+j]);
            *(float4*)(&x2t[row][gi * 64 + tcA * 4]) = o;
        }
    }
    __syncthreads();
    for (int k = 0; k < 64; ++k) {
        float4 a = *(const float4*)(&x2t[k][tcB * 4]);
        float av[4] = {a.x,a.y,a.z,a.w};
        float wv[4];
        #pragma unroll
        for (int j = 0; j < 4; ++j) wv[j] = W31[trB * 4 + j][64 + k];
        #pragma unroll
        for (int i = 0; i < 4; ++i)
            #pragma unroll
            for (int j = 0; j < 4; ++j)
                accB[i][j] = fmaf(av[i], wv[j], accB[i][j]);
    }
    __syncthreads();

    #pragma unroll
    for (int i = 0; i < 4; ++i)
        #pragma unroll
        for (int j = 0; j < 4; ++j)
            cl1buf[tcB * 4 + i][trB * 4 + j] = accB[i][j];
    __syncthreads();
    if (tid < 128) {
        float bv = cl1buf[tid][0]; int bi = 0;
        #pragma unroll
        for (int c = 1; c < 32; ++c) {
            float v = cl1buf[tid][c];
            if (v > bv) { bv = v; bi = c; }
        }
        int n = n0 + tid;
        int w = n / 192, hh = n - w * 192;
        inds1_q[hh * 256 + w] = bi;
    }
}

// ============================================================================
// k_hist: 192 blocks; per-64-seg ballot histogram -> bh[seg][32] (unchanged)
// ============================================================================
__global__ void k_hist(const int* __restrict__ inds1_q, int* __restrict__ bh) {
    int tid = threadIdx.x;
    int n = blockIdx.x * 256 + tid;
    int key = inds1_q[n];
    int lane = tid & 63;
    int cnt = 0;
    for (int k = 0; k < 32; ++k) {
        unsigned long long m = __ballot(key == k);
        if (lane == k) cnt = __popcll(m);
    }
    if (lane < 32) bh[(n >> 6) * 32 + lane] = cnt;
}

// ============================================================================
// k_scanA: 32 blocks (class each); scan 768 seg counts -> ebb, total[k]
// ============================================================================
__global__ void k_scanA(const int* __restrict__ bh, int* __restrict__ ebb,
                        int* __restrict__ total) {
    __shared__ int s[256];
    const int k = blockIdx.x, t = threadIdx.x;
    int v0 = bh[(t * 3 + 0) * 32 + k];
    int v1 = bh[(t * 3 + 1) * 32 + k];
    int v2 = bh[(t * 3 + 2) * 32 + k];
    int sum = v0 + v1 + v2;
    s[t] = sum; __syncthreads();
    for (int d = 1; d < 256; d <<= 1) {
        int x = (t >= d) ? s[t - d] : 0;
        __syncthreads();
        s[t] += x;
        __syncthreads();
    }
    int ex = s[t] - sum;
    ebb[(t * 3 + 0) * 32 + k] = ex;
    ebb[(t * 3 + 1) * 32 + k] = ex + v0;
    ebb[(t * 3 + 2) * 32 + k] = ex + v0 + v1;
    if (t == 255) total[k] = s[255];
}

// ============================================================================
// k_scatter2: deterministic rank scatter, local class bases (unchanged)
// ============================================================================
__global__ void k_scatter2(const int* __restrict__ inds1_q,
                           const int* __restrict__ ebb,
                           const int* __restrict__ total,
                           int* __restrict__ order)
{
    __shared__ int ttot[32];
    const int tid = threadIdx.x;
    if (tid < 32) ttot[tid] = total[tid];
    __syncthreads();
    int n = blockIdx.x * 256 + tid;
    int key = inds1_q[n];
    int lane = tid & 63;
    unsigned long long peers = 0;
    for (int k = 0; k < 32; ++k) {
        unsigned long long m = __ballot(key == k);
        if (key == k) peers = m;
    }
    int rank = __popcll(peers & ((1ull << lane) - 1ull));
    int cbase = 0;
    #pragma unroll
    for (int k = 0; k < 32; ++k) cbase += (k < key) ? ttot[k] : 0;
    order[cbase + ebb[(n >> 6) * 32 + key] + rank] = n;
}

// ============================================================================
// k2h: stage-2 first half (exact R0 baseline)
// ============================================================================
__global__ __launch_bounds__(256, 4) void k2h(
    const float* __restrict__ x_t,
    const float* __restrict__ Wcl22, const float* __restrict__ bcl22,
    const float* __restrict__ Wcl32, const float* __restrict__ bcl32,
    const int* __restrict__ total, const int* __restrict__ order,
    int* __restrict__ ind_ord)
{
    __shared__ float Was[4096];
    __shared__ float Wbs[1024];
    __shared__ int cpre[33];
    __shared__ int cbase[33];
    __shared__ int ttot[32];

    const int tid = threadIdx.x;
    if (tid < 32) ttot[tid] = total[tid];
    __syncthreads();
    if (tid == 0) {
        int s = 0, cb = 0;
        for (int k = 0; k < 32; ++k) {
            cpre[k] = s; cbase[k] = cb;
            int c = ttot[k];
            s += (c + 255) >> 8;
            cb += c;
        }
        cpre[32] = s; cbase[32] = cb;
    }
    __syncthreads();
    const int ci = blockIdx.x;
    if (ci >= cpre[32]) return;
    int cls = 0;
    while (cpre[cls + 1] <= ci) ++cls;
    const int st   = (ci - cpre[cls]) * 256;
    const int npx  = min(256, ttot[cls] - st);
    const int base = cbase[cls] + st;

    {
        const float4* ws = (const float4*)(Wcl22 + cls * 4096);
        #pragma unroll
        for (int j = 0; j < 4; ++j) ((float4*)Was)[j * 256 + tid] = ws[j * 256 + tid];
        ((float4*)Wbs)[tid] = ((const float4*)(Wcl32 + cls * 1024))[tid];
    }
    __syncthreads();

    const int m = order[base + min(tid, npx - 1)];
    const float4* xp = (const float4*)(x_t + (size_t)m * 128);

    float h[32];
    #pragma unroll
    for (int j = 0; j < 32; ++j) h[j] = bcl22[cls * 32 + j];
    #pragma unroll 2
    for (int c4 = 0; c4 < 32; ++c4) {
        float4 xv = xp[c4];
        float xa[4] = {xv.x, xv.y, xv.z, xv.w};
        #pragma unroll
        for (int cc = 0; cc < 4; ++cc) {
            const float* wr = &Was[(c4 * 4 + cc) * 32];
            #pragma unroll
            for (int j = 0; j < 32; ++j) h[j] = fmaf(xa[cc], wr[j], h[j]);
        }
    }
    #pragma unroll
    for (int j = 0; j < 32; ++j) h[j] = lrelu(h[j]);

    float g[32];
    #pragma unroll
    for (int j = 0; j < 32; ++j) g[j] = bcl32[cls * 32 + j];
    #pragma unroll 2
    for (int c = 0; c < 32; ++c) {
        float hv = h[c];
        const float* wr = &Wbs[c * 32];
        #pragma unroll
        for (int j = 0; j < 32; ++j) g[j] = fmaf(hv, wr[j], g[j]);
    }
    float bv = g[0]; int bi = 0;
    #pragma unroll
    for (int j = 1; j < 32; ++j)
        if (g[j] > bv) { bv = g[j]; bi = j; }     // strict > = first-max (np.argmax)
    if (tid < npx) ind_ord[base + tid] = cls * 32 + bi;
}

// ============================================================================
// k2r: stage-2 second half (exact R0 baseline)
// ============================================================================
__global__ __launch_bounds__(256, 4) void k2r(
    const float* __restrict__ r_t,
    const float* __restrict__ Wr2,  const float* __restrict__ br2,
    const float* __restrict__ Wr3,  const float* __restrict__ br3,
    const int* __restrict__ total, const int* __restrict__ order,
    const int* __restrict__ ind_ord,
    float* __restrict__ out)
{
    __shared__ float Wcs[4096];
    __shared__ int cpre[33];
    __shared__ int cbase[33];
    __shared__ int ttot[32];

    const int tid = threadIdx.x;
    if (tid < 32) ttot[tid] = total[tid];
    __syncthreads();
    if (tid == 0) {
        int s = 0, cb = 0;
        for (int k = 0; k < 32; ++k) {
            cpre[k] = s; cbase[k] = cb;
            int c = ttot[k];
            s += (c + 255) >> 8;
            cb += c;
        }
        cpre[32] = s; cbase[32] = cb;
    }
    __syncthreads();
    const int ci = blockIdx.x;
    if (ci >= cpre[32]) return;
    int cls = 0;
    while (cpre[cls + 1] <= ci) ++cls;
    const int st   = (ci - cpre[cls]) * 256;
    const int npx  = min(256, ttot[cls] - st);
    const int base = cbase[cls] + st;
    const int sup  = cls >> 2;

    {
        const float4* ws = (const float4*)(Wr2 + sup * 4096);
        #pragma unroll
        for (int j = 0; j < 4; ++j) ((float4*)Wcs)[j * 256 + tid] = ws[j * 256 + tid];
    }
    __syncthreads();

    const int li  = min(tid, npx - 1);
    const int m   = order[base + li];
    const int ind = ind_ord[base + li];
    const float4* rp = (const float4*)(r_t + (size_t)m * 128);

    float r2[32];
    #pragma unroll
    for (int j = 0; j < 32; ++j) r2[j] = br2[sup * 32 + j];
    #pragma unroll 2
    for (int c4 = 0; c4 < 32; ++c4) {
        float4 rv = rp[c4];
        float ra[4] = {rv.x, rv.y, rv.z, rv.w};
        #pragma unroll
        for (int cc = 0; cc < 4; ++cc) {
            const float* wr = &Wcs[(c4 * 4 + cc) * 32];
            #pragma unroll
            for (int j = 0; j < 32; ++j) r2[j] = fmaf(ra[cc], wr[j], r2[j]);
        }
    }

    float reg = br3[ind];
    const float* __restrict__ w3 = Wr3 + ind * 32;
    #pragma unroll
    for (int j = 0; j < 32; ++j) reg = fmaf(lrelu(r2[j]), w3[j], reg);

    if (tid < npx) out[m] = ((float)ind + reg) * (1.0f / 1024.0f);
}

extern "C" void kernel_launch(void* const* d_in, const int* in_sizes, int n_in,
                              void* d_out, int out_size, void* d_ws, size_t ws_size,
                              hipStream_t stream)
{
    const float* X     = (const float*)d_in[0];
    const float* Wm1   = (const float*)d_in[1];
    const float* bm1   = (const float*)d_in[2];
    const float* Wm2   = (const float*)d_in[3];
    const float* bm2   = (const float*)d_in[4];
    const float* Wm3   = (const float*)d_in[5];
    const float* bm3   = (const float*)d_in[6];
    const float* Wcl1  = (const float*)d_in[7];
    const float* bcl1  = (const float*)d_in[8];
    const float* Wcl21 = (const float*)d_in[9];
    const float* bcl21 = (const float*)d_in[10];
    const float* Wcl31 = (const float*)d_in[11];
    const float* bcl31 = (const float*)d_in[12];
    const float* Wcl22 = (const float*)d_in[13];
    const float* bcl22 = (const float*)d_in[14];
    const float* Wcl32 = (const float*)d_in[15];
    const float* bcl32 = (const float*)d_in[16];
    const float* Wr1   = (const float*)d_in[17];
    const float* br1   = (const float*)d_in[18];
    const float* Wr2   = (const float*)d_in[19];
    const float* br2   = (const float*)d_in[20];
    const float* Wr3   = (const float*)d_in[21];
    const float* br3   = (const float*)d_in[22];
    float* out = (float*)d_out;

    float* x_t   = (float*)d_ws;
    float* r_t   = x_t + (size_t)NPIX * 128;
    int* inds1_q = (int*)(r_t + (size_t)NPIX * 128);
    int* order   = inds1_q + NPIX;
    int* ind_ord = order + NPIX;
    int* bh      = ind_ord + NPIX;      // [768][32]
    int* ebb     = bh + NSEG * 32;      // [768][32]
    int* total   = ebb + NSEG * 32;     // [32]

    k_fused1<<<dim3(NPIX / 128, 3), 256, 0, stream>>>(X, Wcl1, bcl1, Wr1, br1,
                                                      Wm1, bm1, Wm2, bm2, Wm3, bm3,
                                                      x_t, r_t, out);
    k1b<<<NPIX / 128, 256, 0, stream>>>(x_t, Wcl21, bcl21, Wcl31, bcl31, inds1_q);
    k_hist<<<NPIX / 256, 256, 0, stream>>>(inds1_q, bh);
    k_scanA<<<32, 256, 0, stream>>>(bh, ebb, total);
    k_scatter2<<<NPIX / 256, 256, 0, stream>>>(inds1_q, ebb, total, order);
    // 256-px chunks: worst case sum ceil = 192 + 31 = 223 -> grid 224 covers all
    k2h<<<224, 256, 0, stream>>>(x_t, Wcl22, bcl22, Wcl32, bcl32, total, order, ind_ord);
    k2r<<<224, 256, 0, stream>>>(r_t, Wr2, br2, Wr3, br3, total, order, ind_ord, out);
}